// Round 15
// baseline (32.315 us; speedup 1.0000x reference)
//
#include <hip/hip_runtime.h>

#define Bn  4
#define Cn  64
#define Hn  96
#define Wn  96
#define Con 64
#define Kk  9
#define HW  (Hn*Wn)     // 9216
#define PIX 16
#define CK  (Cn*Kk)     // 576
#define NTILE (HW/PIX)  // 576

typedef __attribute__((ext_vector_type(8))) short bf16x8;
typedef __attribute__((ext_vector_type(8))) unsigned short u16x8;
typedef __attribute__((ext_vector_type(4))) float f32x4;

static __device__ __forceinline__ float bf2f(ushort u) {
    return __uint_as_float(((unsigned int)u) << 16);
}
static __device__ __forceinline__ ushort f2bf(float f) {
    unsigned int u = __float_as_uint(f);
    u += 0x7FFFu + ((u >> 16) & 1u);   // RNE
    return (ushort)(u >> 16);
}

static __device__ __forceinline__ bf16x8 blend8(
    float w00, float w01, float w10, float w11,
    u16x8 g00, u16x8 g01, u16x8 g10, u16x8 g11)
{
    u16x8 r;
    #pragma unroll
    for (int j = 0; j < 8; ++j) {
        const float v = w00 * bf2f(g00[j]) + w01 * bf2f(g01[j])
                      + w10 * bf2f(g10[j]) + w11 * bf2f(g11[j]);
        r[j] = f2bf(v);
    }
    return __builtin_bit_cast(bf16x8, r);
}

// ---------------- prep (merged): blocks 0..575 transpose NCHW->NHWC bf16,
// blocks 576..719: weight f32 [o][c*9+k] -> bf16 lane-linear wb2:
//   wb2[((s*18 + kk)*64 + l)*8 + j] = W[o = s*16+(l&15)][ck = kk*32+(l>>4)*8+j]
__global__ __launch_bounds__(256) void dcnv2_prep(
    const float* __restrict__ in, const float* __restrict__ w,
    ushort* __restrict__ nhwc, ushort* __restrict__ wb2)
{
    const int t = threadIdx.x;
    if (blockIdx.x < 576) {
        __shared__ ushort tile[64][66];
        const int bid = blockIdx.x;
        const int b  = bid / 144;
        const int s0 = (bid % 144) * 64;
        const float* ib = in + (size_t)b * Cn * HW;
        #pragma unroll
        for (int i = 0; i < 16; ++i) {
            const int c = i * 4 + (t >> 6);
            tile[t & 63][c] = f2bf(ib[(size_t)c * HW + s0 + (t & 63)]);
        }
        __syncthreads();
        ushort* ob = nhwc + ((size_t)b * HW + s0) * 64;
        #pragma unroll
        for (int i = 0; i < 16; ++i) {
            const int s = i * 4 + (t >> 6);
            ob[s * 64 + (t & 63)] = tile[s][t & 63];
        }
    } else {
        const int e = (blockIdx.x - 576) * 256 + t;   // dst element index
        if (e < Con * CK) {
            const int j  = e & 7;
            const int l  = (e >> 3) & 63;
            const int sk = e >> 9;            // s*18 + kk, 0..71
            const int s  = sk / 18;
            const int kk = sk - s * 18;
            const int o  = s * 16 + (l & 15);
            const int ck = kk * 32 + (l >> 4) * 8 + j;
            const int kt = ck >> 6;
            const int c  = ck & 63;
            wb2[e] = f2bf(w[(size_t)o * CK + c * Kk + kt]);
        }
    }
}

// ---------------- main: 3 waves/block, wave u owns tap row u; TWO adjacent
//   16-px tiles per block; per-wave weight frags register-pinned (loaded once) ----------------
__global__ __launch_bounds__(192)
__attribute__((amdgpu_waves_per_eu(2, 2)))
void dcnv2_main(
    const ushort* __restrict__ nhwc,   // [B][HW][64] bf16
    const ushort* __restrict__ wb2,    // lane-linear weights (see prep)
    const float*  __restrict__ offset,
    const float*  __restrict__ mask,
    const float*  __restrict__ bias,
    float* __restrict__ out)
{
    __shared__ u16x8 stage[3][512];      // 24 KB: per-wave corner stage (reused across tiles)
    __shared__ float red[2][2][64][20];  // 20.5 KB: [tile][wave-1][lane][16]

    const int t    = threadIdx.x;
    const int lane = t & 63;
    const int u    = t >> 6;             // wave 0..2 -> tap row
    const int orig = blockIdx.x;
    const int pair = (orig & 7) * 144 + (orig >> 3);   // XCD-bijective (1152=8*144)
    const int tile0 = pair * 2;          // tiles tile0, tile0+1: same row, adjacent 16-px segs
    const int b    = tile0 / NTILE;
    const int t16  = tile0 % NTILE;      // even; no row crossing (6 segs/row)
    const int pix0 = t16 * PIX;
    const int ho   = pix0 / Wn;
    const int wo0  = pix0 % Wn;
    const int px   = lane & 15;
    const int q    = lane >> 4;
    const int px8  = lane >> 3;          // gather role: pixel sub-index
    const int jj   = lane & 7;           // gather role: 16B chunk
    const int fpx  = px & 7;             // read-swizzle key

    // ---- prefetch offset/mask for both tiles x this wave's 3 taps (18 loads) ----
    const float* __restrict__ obase = offset + (size_t)b * 2 * Kk * HW;
    const float* __restrict__ mbase = mask   + (size_t)b * Kk * HW;
    float dyv[2][3], dxv[2][3], mmv[2][3];
    #pragma unroll
    for (int tt = 0; tt < 2; ++tt) {
        const int sp = ho * Wn + wo0 + tt * 16 + px;
        #pragma unroll
        for (int j = 0; j < 3; ++j) {
            const int k = u * 3 + j;
            dyv[tt][j] = obase[(size_t)(2 * k) * HW + sp];
            dxv[tt][j] = obase[(size_t)(2 * k + 1) * HW + sp];
            mmv[tt][j] = mbase[(size_t)k * HW + sp];
        }
    }

    // ---- load this wave's 24 weight frags ONCE; pin in VGPRs ----
    const ushort* __restrict__ wl = wb2 + lane * 8;
    bf16x8 wf[3][2][4];                  // [tap j][kk-half][o-strip]
    #pragma unroll
    for (int j = 0; j < 3; ++j) {
        const int kk0 = 2 * (u * 3 + j);
        #pragma unroll
        for (int h = 0; h < 2; ++h) {
            #pragma unroll
            for (int s = 0; s < 4; ++s)
                wf[j][h][s] = *(const bf16x8*)(wl + (size_t)(s * 18 + kk0 + h) * 512);
        }
    }
    #pragma unroll
    for (int j = 0; j < 3; ++j)
        #pragma unroll
        for (int h = 0; h < 2; ++h)
            #pragma unroll
            for (int s = 0; s < 4; ++s)
                asm volatile("" : "+v"(wf[j][h][s]));

    const ushort* __restrict__ nb = nhwc + (size_t)b * HW * 64;

    f32x4 a0_0 = {0,0,0,0}, a0_1 = {0,0,0,0}, a0_2 = {0,0,0,0}, a0_3 = {0,0,0,0};
    f32x4 a1_0 = {0,0,0,0}, a1_1 = {0,0,0,0}, a1_2 = {0,0,0,0}, a1_3 = {0,0,0,0};

    #pragma unroll
    for (int tt = 0; tt < 2; ++tt) {
        const int wo = wo0 + tt * 16 + px;
        #pragma unroll
        for (int j = 0; j < 3; ++j) {
            // ---- bilinear params; tap row = u, tap col = j ----
            const float py  = dyv[tt][j] + (float)u + (float)(ho - 1);
            const float pxf = dxv[tt][j] + (float)j + (float)(wo - 1);
            const float fy = floorf(py), fx = floorf(pxf);
            const int iy0 = (int)fy, ix0 = (int)fx;
            const int iy1 = iy0 + 1, ix1 = ix0 + 1;
            const float wy = py - fy, wx = pxf - fx;
            const float vy0 = (iy0 >= 0 && iy0 < Hn) ? 1.f : 0.f;
            const float vy1 = (iy1 >= 0 && iy1 < Hn) ? 1.f : 0.f;
            const float vx0 = (ix0 >= 0 && ix0 < Wn) ? 1.f : 0.f;
            const float vx1 = (ix1 >= 0 && ix1 < Wn) ? 1.f : 0.f;
            const int cy0 = min(max(iy0, 0), Hn - 1), cy1 = min(max(iy1, 0), Hn - 1);
            const int cx0 = min(max(ix0, 0), Wn - 1), cx1 = min(max(ix1, 0), Wn - 1);
            const float m = mmv[tt][j];
            const float w00 = m * (1.f - wy) * (1.f - wx) * vy0 * vx0;
            const float w01 = m * (1.f - wy) * wx         * vy0 * vx1;
            const float w10 = m * wy         * (1.f - wx) * vy1 * vx0;
            const float w11 = m * wy         * wx         * vy1 * vx1;
            const int ac0 = (cy0 * Wn + cx0) * 64;
            const int ac1 = (cy0 * Wn + cx1) * 64;
            const int ac2 = (cy1 * Wn + cx0) * 64;
            const int ac3 = (cy1 * Wn + cx1) * 64;

            // ---- gather: 8 instrs, each = 8 corners x full 128B line ----
            #pragma unroll
            for (int c = 0; c < 4; ++c) {
                const int a = (c == 0) ? ac0 : (c == 1) ? ac1 : (c == 2) ? ac2 : ac3;
                #pragma unroll
                for (int hh = 0; hh < 2; ++hh) {
                    const int p    = px8 + hh * 8;
                    const int base = __shfl(a, p);
                    const u16x8 g  = *(const u16x8*)(nb + base + jj * 8);
                    stage[u][(p * 4 + c) * 8 + (jj ^ (p & 7))] = g;
                }
            }

            // ---- read back own pixel's 4 corners (swizzled) ----
            const int E0 = px * 4 + 0, E1 = px * 4 + 1, E2 = px * 4 + 2, E3 = px * 4 + 3;
            const u16x8 ga0 = stage[u][E0 * 8 + (q ^ fpx)];
            const u16x8 ga1 = stage[u][E1 * 8 + (q ^ fpx)];
            const u16x8 ga2 = stage[u][E2 * 8 + (q ^ fpx)];
            const u16x8 ga3 = stage[u][E3 * 8 + (q ^ fpx)];
            const u16x8 gb0 = stage[u][E0 * 8 + ((q + 4) ^ fpx)];
            const u16x8 gb1 = stage[u][E1 * 8 + ((q + 4) ^ fpx)];
            const u16x8 gb2 = stage[u][E2 * 8 + ((q + 4) ^ fpx)];
            const u16x8 gb3 = stage[u][E3 * 8 + ((q + 4) ^ fpx)];

            const bf16x8 bfa = blend8(w00, w01, w10, w11, ga0, ga1, ga2, ga3);
            const bf16x8 bfb = blend8(w00, w01, w10, w11, gb0, gb1, gb2, gb3);

            if (tt == 0) {
                a0_0 = __builtin_amdgcn_mfma_f32_16x16x32_bf16(wf[j][0][0], bfa, a0_0, 0, 0, 0);
                a0_0 = __builtin_amdgcn_mfma_f32_16x16x32_bf16(wf[j][1][0], bfb, a0_0, 0, 0, 0);
                a0_1 = __builtin_amdgcn_mfma_f32_16x16x32_bf16(wf[j][0][1], bfa, a0_1, 0, 0, 0);
                a0_1 = __builtin_amdgcn_mfma_f32_16x16x32_bf16(wf[j][1][1], bfb, a0_1, 0, 0, 0);
                a0_2 = __builtin_amdgcn_mfma_f32_16x16x32_bf16(wf[j][0][2], bfa, a0_2, 0, 0, 0);
                a0_2 = __builtin_amdgcn_mfma_f32_16x16x32_bf16(wf[j][1][2], bfb, a0_2, 0, 0, 0);
                a0_3 = __builtin_amdgcn_mfma_f32_16x16x32_bf16(wf[j][0][3], bfa, a0_3, 0, 0, 0);
                a0_3 = __builtin_amdgcn_mfma_f32_16x16x32_bf16(wf[j][1][3], bfb, a0_3, 0, 0, 0);
            } else {
                a1_0 = __builtin_amdgcn_mfma_f32_16x16x32_bf16(wf[j][0][0], bfa, a1_0, 0, 0, 0);
                a1_0 = __builtin_amdgcn_mfma_f32_16x16x32_bf16(wf[j][1][0], bfb, a1_0, 0, 0, 0);
                a1_1 = __builtin_amdgcn_mfma_f32_16x16x32_bf16(wf[j][0][1], bfa, a1_1, 0, 0, 0);
                a1_1 = __builtin_amdgcn_mfma_f32_16x16x32_bf16(wf[j][1][1], bfb, a1_1, 0, 0, 0);
                a1_2 = __builtin_amdgcn_mfma_f32_16x16x32_bf16(wf[j][0][2], bfa, a1_2, 0, 0, 0);
                a1_2 = __builtin_amdgcn_mfma_f32_16x16x32_bf16(wf[j][1][2], bfb, a1_2, 0, 0, 0);
                a1_3 = __builtin_amdgcn_mfma_f32_16x16x32_bf16(wf[j][0][3], bfa, a1_3, 0, 0, 0);
                a1_3 = __builtin_amdgcn_mfma_f32_16x16x32_bf16(wf[j][1][3], bfb, a1_3, 0, 0, 0);
            }
        }
    }

    // ---- reduce: waves 1,2 park partials; wave 0 sums + bias + stores both tiles ----
    if (u > 0) {
        #pragma unroll
        for (int tt = 0; tt < 2; ++tt) {
            float* rp = &red[tt][u - 1][lane][0];
            *(f32x4*)(rp + 0)  = tt ? a1_0 : a0_0;
            *(f32x4*)(rp + 4)  = tt ? a1_1 : a0_1;
            *(f32x4*)(rp + 8)  = tt ? a1_2 : a0_2;
            *(f32x4*)(rp + 12) = tt ? a1_3 : a0_3;
        }
    }
    __syncthreads();
    if (u == 0) {
        const int orow = q * 4;
        #pragma unroll
        for (int tt = 0; tt < 2; ++tt) {
            float* __restrict__ op = out + (size_t)b * Con * HW + pix0 + tt * 16 + px;
            const float* rp0 = &red[tt][0][lane][0];
            const float* rp1 = &red[tt][1][lane][0];
            #pragma unroll
            for (int s = 0; s < 4; ++s) {
                f32x4 a;
                if (tt == 0) { a = (s == 0) ? a0_0 : (s == 1) ? a0_1 : (s == 2) ? a0_2 : a0_3; }
                else         { a = (s == 0) ? a1_0 : (s == 1) ? a1_1 : (s == 2) ? a1_2 : a1_3; }
                const f32x4 r0 = *(const f32x4*)(rp0 + s * 4);
                const f32x4 r1 = *(const f32x4*)(rp1 + s * 4);
                const f32x4 bv = *(const f32x4*)&bias[s * 16 + orow];
                #pragma unroll
                for (int r = 0; r < 4; ++r)
                    op[(size_t)(s * 16 + orow + r) * HW] = a[r] + r0[r] + r1[r] + bv[r];
            }
        }
    }
}

// ---------------- fallback (round-1 fp32 fused, used only if ws too small) ----------------
__global__ __launch_bounds__(256) void dcnv2_fused(
    const float* __restrict__ input, const float* __restrict__ offset,
    const float* __restrict__ mask, const float* __restrict__ weight,
    const float* __restrict__ bias, float* __restrict__ out)
{
    __shared__ float s_w[PIX*Kk][4];
    __shared__ int   s_a[PIX*Kk][4];
    __shared__ float s_samp[CK*PIX];
    const int t = threadIdx.x, blk = blockIdx.x;
    const int b = blk / NTILE, tile = blk % NTILE;
    const int pix0 = tile * PIX, ho = pix0 / Wn, wo0 = pix0 % Wn;
    if (t < PIX*Kk) {
        const int p = t / Kk, k = t - p*Kk, wo = wo0 + p, sp = ho*Wn + wo;
        const float dy = offset[(size_t)(b*2*Kk + 2*k)*HW + sp];
        const float dx = offset[(size_t)(b*2*Kk + 2*k + 1)*HW + sp];
        const float m  = mask[(size_t)(b*Kk + k)*HW + sp];
        const float py = dy + (float)(k/3) + (float)(ho - 1);
        const float px = dx + (float)(k%3) + (float)(wo - 1);
        const float fy = floorf(py), fx = floorf(px);
        const int iy0 = (int)fy, ix0 = (int)fx, iy1 = iy0+1, ix1 = ix0+1;
        const float wy = py - fy, wx = px - fx;
        const float vy0 = (iy0>=0 && iy0<Hn)?1.f:0.f, vy1 = (iy1>=0 && iy1<Hn)?1.f:0.f;
        const float vx0 = (ix0>=0 && ix0<Wn)?1.f:0.f, vx1 = (ix1>=0 && ix1<Wn)?1.f:0.f;
        const int cy0 = min(max(iy0,0),Hn-1), cy1 = min(max(iy1,0),Hn-1);
        const int cx0 = min(max(ix0,0),Wn-1), cx1 = min(max(ix1,0),Wn-1);
        s_w[t][0]=m*(1.f-wy)*(1.f-wx)*vy0*vx0; s_w[t][1]=m*(1.f-wy)*wx*vy0*vx1;
        s_w[t][2]=m*wy*(1.f-wx)*vy1*vx0;       s_w[t][3]=m*wy*wx*vy1*vx1;
        s_a[t][0]=cy0*Wn+cx0; s_a[t][1]=cy0*Wn+cx1; s_a[t][2]=cy1*Wn+cx0; s_a[t][3]=cy1*Wn+cx1;
    }
    __syncthreads();
    {
        const float* inb = input + (size_t)b*Cn*HW;
        #pragma unroll 4
        for (int e = t; e < CK*PIX; e += 256) {
            const int ck = e >> 4, p = e & 15, c = ck / 9, k = ck - c*9, pk = p*Kk + k;
            const float* ic = inb + (size_t)c*HW;
            s_samp[ck*PIX + p] = s_w[pk][0]*ic[s_a[pk][0]] + s_w[pk][1]*ic[s_a[pk][1]]
                               + s_w[pk][2]*ic[s_a[pk][2]] + s_w[pk][3]*ic[s_a[pk][3]];
        }
    }
    __syncthreads();
    const int o = t & 63, pg = t >> 6;
    const float4* wrow = (const float4*)(weight + (size_t)o*CK);
    float ax=0.f, ay=0.f, az=0.f, aw=0.f;
    #pragma unroll 4
    for (int qq = 0; qq < CK/4; ++qq) {
        const float4 wv = wrow[qq];
        const float4 s0 = *(const float4*)&s_samp[(4*qq+0)*PIX + pg*4];
        const float4 s1 = *(const float4*)&s_samp[(4*qq+1)*PIX + pg*4];
        const float4 s2 = *(const float4*)&s_samp[(4*qq+2)*PIX + pg*4];
        const float4 s3 = *(const float4*)&s_samp[(4*qq+3)*PIX + pg*4];
        ax += wv.x*s0.x + wv.y*s1.x + wv.z*s2.x + wv.w*s3.x;
        ay += wv.x*s0.y + wv.y*s1.y + wv.z*s2.y + wv.w*s3.y;
        az += wv.x*s0.z + wv.y*s1.z + wv.z*s2.z + wv.w*s3.z;
        aw += wv.x*s0.w + wv.y*s1.w + wv.z*s2.w + wv.w*s3.w;
    }
    const float bo = bias[o];
    float* op = out + (size_t)(b*Con + o)*HW + pix0 + pg*4;
    op[0]=ax+bo; op[1]=ay+bo; op[2]=az+bo; op[3]=aw+bo;
}

extern "C" void kernel_launch(void* const* d_in, const int* in_sizes, int n_in,
                              void* d_out, int out_size, void* d_ws, size_t ws_size,
                              hipStream_t stream) {
    const float* input  = (const float*)d_in[0];
    const float* offset = (const float*)d_in[1];
    const float* mask   = (const float*)d_in[2];
    const float* weight = (const float*)d_in[3];
    const float* bias   = (const float*)d_in[4];
    float* out = (float*)d_out;

    const size_t nhwc_bytes = (size_t)Bn * HW * 64 * 2;          // 4,718,592
    const size_t wb_bytes   = (size_t)Con * CK * 2;              // 73,728
    if (ws_size >= nhwc_bytes + wb_bytes) {
        ushort* nhwc = (ushort*)d_ws;
        ushort* wbuf = (ushort*)((char*)d_ws + nhwc_bytes);
        hipLaunchKernelGGL(dcnv2_prep, dim3(720), dim3(256), 0, stream,
                           input, weight, nhwc, wbuf);
        hipLaunchKernelGGL(dcnv2_main, dim3(1152), dim3(192), 0, stream,
                           nhwc, wbuf, offset, mask, bias, out);
    } else {
        hipLaunchKernelGGL(dcnv2_fused, dim3(Bn * NTILE), dim3(256), 0, stream,
                           input, offset, mask, weight, bias, out);
    }
}

// Round 16
// 28.067 us; speedup vs baseline: 1.1513x; 1.1513x over previous
//
#include <hip/hip_runtime.h>

#define Bn  4
#define Cn  64
#define Hn  96
#define Wn  96
#define Con 64
#define Kk  9
#define HW  (Hn*Wn)     // 9216
#define PIX 16
#define CK  (Cn*Kk)     // 576
#define NTILE (HW/PIX)  // 576

typedef __attribute__((ext_vector_type(8))) short bf16x8;
typedef __attribute__((ext_vector_type(8))) unsigned short u16x8;
typedef __attribute__((ext_vector_type(4))) float f32x4;

static __device__ __forceinline__ float bf2f(ushort u) {
    return __uint_as_float(((unsigned int)u) << 16);
}
static __device__ __forceinline__ ushort f2bf(float f) {
    unsigned int u = __float_as_uint(f);
    u += 0x7FFFu + ((u >> 16) & 1u);   // RNE
    return (ushort)(u >> 16);
}

static __device__ __forceinline__ bf16x8 blend8(
    float w00, float w01, float w10, float w11,
    u16x8 g00, u16x8 g01, u16x8 g10, u16x8 g11)
{
    u16x8 r;
    #pragma unroll
    for (int j = 0; j < 8; ++j) {
        const float v = w00 * bf2f(g00[j]) + w01 * bf2f(g01[j])
                      + w10 * bf2f(g10[j]) + w11 * bf2f(g11[j]);
        r[j] = f2bf(v);
    }
    return __builtin_bit_cast(bf16x8, r);
}

// ---------------- prep (merged): blocks 0..575 transpose NCHW->NHWC bf16,
// blocks 576..719: weight f32 [o][c*9+k] -> bf16 lane-linear wb2:
//   wb2[((s*18 + kk)*64 + l)*8 + j] = W[o = s*16+(l&15)][ck = kk*32+(l>>4)*8+j]
__global__ __launch_bounds__(256) void dcnv2_prep(
    const float* __restrict__ in, const float* __restrict__ w,
    ushort* __restrict__ nhwc, ushort* __restrict__ wb2)
{
    const int t = threadIdx.x;
    if (blockIdx.x < 576) {
        __shared__ ushort tile[64][66];
        const int bid = blockIdx.x;
        const int b  = bid / 144;
        const int s0 = (bid % 144) * 64;
        const float* ib = in + (size_t)b * Cn * HW;
        #pragma unroll
        for (int i = 0; i < 16; ++i) {
            const int c = i * 4 + (t >> 6);
            tile[t & 63][c] = f2bf(ib[(size_t)c * HW + s0 + (t & 63)]);
        }
        __syncthreads();
        ushort* ob = nhwc + ((size_t)b * HW + s0) * 64;
        #pragma unroll
        for (int i = 0; i < 16; ++i) {
            const int s = i * 4 + (t >> 6);
            ob[s * 64 + (t & 63)] = tile[s][t & 63];
        }
    } else {
        const int e = (blockIdx.x - 576) * 256 + t;   // dst element index
        if (e < Con * CK) {
            const int j  = e & 7;
            const int l  = (e >> 3) & 63;
            const int sk = e >> 9;            // s*18 + kk, 0..71
            const int s  = sk / 18;
            const int kk = sk - s * 18;
            const int o  = s * 16 + (l & 15);
            const int ck = kk * 32 + (l >> 4) * 8 + j;
            const int kt = ck >> 6;
            const int c  = ck & 63;
            wb2[e] = f2bf(w[(size_t)o * CK + c * Kk + kt]);
        }
    }
}

// ---------------- main: 3 waves/block; wave u owns tap row u (taps 3u..3u+2);
//                  full-128B line gathers + swizzled LDS stage + dense weights ----------------
__global__ __launch_bounds__(192) void dcnv2_main(
    const ushort* __restrict__ nhwc,   // [B][HW][64] bf16
    const ushort* __restrict__ wb2,    // lane-linear weights (see prep)
    const float*  __restrict__ offset,
    const float*  __restrict__ mask,
    const float*  __restrict__ bias,
    float* __restrict__ out)
{
    __shared__ u16x8 stage[3][512];    // 24 KB: per-wave corner stage
    __shared__ float red[2][64][20];   // 10.25 KB: partials of waves 1,2

    const int t    = threadIdx.x;
    const int lane = t & 63;
    const int u    = t >> 6;           // wave 0..2 -> tap row
    const int orig = blockIdx.x;
    const int tile = (orig & 7) * 288 + (orig >> 3);   // XCD-bijective (2304=8*288)
    const int b    = tile / NTILE;
    const int t16  = tile % NTILE;
    const int pix0 = t16 * PIX;
    const int ho   = pix0 / Wn;
    const int wo0  = pix0 % Wn;
    const int px   = lane & 15;
    const int q    = lane >> 4;
    const int px8  = lane >> 3;        // gather role: pixel sub-index
    const int jj   = lane & 7;         // gather role: 16B chunk
    const int fpx  = px & 7;           // read-swizzle key
    const int wo   = wo0 + px;
    const int sp   = ho * Wn + wo;

    // ---- prefetch this wave's 3 taps' offset/mask (9 independent loads) ----
    const float* __restrict__ obp = offset + (size_t)b * 2 * Kk * HW + sp;
    const float* __restrict__ mbp = mask   + (size_t)b * Kk * HW + sp;
    float dyv[3], dxv[3], mmv[3];
    #pragma unroll
    for (int j = 0; j < 3; ++j) {
        const int k = u * 3 + j;
        dyv[j] = obp[(size_t)(2 * k) * HW];
        dxv[j] = obp[(size_t)(2 * k + 1) * HW];
        mmv[j] = mbp[(size_t)k * HW];
    }

    const ushort* __restrict__ nb = nhwc + (size_t)b * HW * 64;
    const ushort* __restrict__ wl = wb2 + lane * 8;    // lane-linear base

    f32x4 acc0 = {0.f,0.f,0.f,0.f}, acc1 = {0.f,0.f,0.f,0.f};
    f32x4 acc2 = {0.f,0.f,0.f,0.f}, acc3 = {0.f,0.f,0.f,0.f};

    #pragma unroll
    for (int j = 0; j < 3; ++j) {
        const int k = u * 3 + j;       // tap row = u, tap col = j
        // ---- bilinear params for this lane's pixel ----
        const float py  = dyv[j] + (float)u + (float)(ho - 1);
        const float pxf = dxv[j] + (float)j + (float)(wo - 1);
        const float fy = floorf(py), fx = floorf(pxf);
        const int iy0 = (int)fy, ix0 = (int)fx;
        const int iy1 = iy0 + 1, ix1 = ix0 + 1;
        const float wy = py - fy, wx = pxf - fx;
        const float vy0 = (iy0 >= 0 && iy0 < Hn) ? 1.f : 0.f;
        const float vy1 = (iy1 >= 0 && iy1 < Hn) ? 1.f : 0.f;
        const float vx0 = (ix0 >= 0 && ix0 < Wn) ? 1.f : 0.f;
        const float vx1 = (ix1 >= 0 && ix1 < Wn) ? 1.f : 0.f;
        const int cy0 = min(max(iy0, 0), Hn - 1), cy1 = min(max(iy1, 0), Hn - 1);
        const int cx0 = min(max(ix0, 0), Wn - 1), cx1 = min(max(ix1, 0), Wn - 1);
        const float m = mmv[j];
        const float w00 = m * (1.f - wy) * (1.f - wx) * vy0 * vx0;
        const float w01 = m * (1.f - wy) * wx         * vy0 * vx1;
        const float w10 = m * wy         * (1.f - wx) * vy1 * vx0;
        const float w11 = m * wy         * wx         * vy1 * vx1;
        // corner base addresses (channel 0), element units
        const int ac0 = (cy0 * Wn + cx0) * 64;
        const int ac1 = (cy0 * Wn + cx1) * 64;
        const int ac2 = (cy1 * Wn + cx0) * 64;
        const int ac3 = (cy1 * Wn + cx1) * 64;

        // ---- gather: 8 instrs, each = 8 corners x full 128B (aligned whole lines) ----
        #pragma unroll
        for (int c = 0; c < 4; ++c) {
            const int a = (c == 0) ? ac0 : (c == 1) ? ac1 : (c == 2) ? ac2 : ac3;
            #pragma unroll
            for (int hh = 0; hh < 2; ++hh) {
                const int p    = px8 + hh * 8;           // pixel this lane serves
                const int base = __shfl(a, p);           // corner c addr of pixel p
                const u16x8 g  = *(const u16x8*)(nb + base + jj * 8);
                stage[u][(p * 4 + c) * 8 + (jj ^ (p & 7))] = g;
            }
        }

        // ---- 8 afrag loads, fully-coalesced 1KB each (lane-linear wb2) ----
        const ushort* wk = wl + (size_t)(2 * k) * 512;
        const bf16x8 af0a = *(const bf16x8*)(wk);
        const bf16x8 af0b = *(const bf16x8*)(wk + 512);
        const bf16x8 af1a = *(const bf16x8*)(wk + 18 * 512);
        const bf16x8 af1b = *(const bf16x8*)(wk + 19 * 512);
        const bf16x8 af2a = *(const bf16x8*)(wk + 36 * 512);
        const bf16x8 af2b = *(const bf16x8*)(wk + 37 * 512);
        const bf16x8 af3a = *(const bf16x8*)(wk + 54 * 512);
        const bf16x8 af3b = *(const bf16x8*)(wk + 55 * 512);

        // ---- read back own pixel's 4 corners (swizzled), chunks q and q+4 ----
        const int E0 = px * 4 + 0, E1 = px * 4 + 1, E2 = px * 4 + 2, E3 = px * 4 + 3;
        const u16x8 ga0 = stage[u][E0 * 8 + (q ^ fpx)];
        const u16x8 ga1 = stage[u][E1 * 8 + (q ^ fpx)];
        const u16x8 ga2 = stage[u][E2 * 8 + (q ^ fpx)];
        const u16x8 ga3 = stage[u][E3 * 8 + (q ^ fpx)];
        const u16x8 gb0 = stage[u][E0 * 8 + ((q + 4) ^ fpx)];
        const u16x8 gb1 = stage[u][E1 * 8 + ((q + 4) ^ fpx)];
        const u16x8 gb2 = stage[u][E2 * 8 + ((q + 4) ^ fpx)];
        const u16x8 gb3 = stage[u][E3 * 8 + ((q + 4) ^ fpx)];

        const bf16x8 bfa = blend8(w00, w01, w10, w11, ga0, ga1, ga2, ga3);
        const bf16x8 bfb = blend8(w00, w01, w10, w11, gb0, gb1, gb2, gb3);

        acc0 = __builtin_amdgcn_mfma_f32_16x16x32_bf16(af0a, bfa, acc0, 0, 0, 0);
        acc0 = __builtin_amdgcn_mfma_f32_16x16x32_bf16(af0b, bfb, acc0, 0, 0, 0);
        acc1 = __builtin_amdgcn_mfma_f32_16x16x32_bf16(af1a, bfa, acc1, 0, 0, 0);
        acc1 = __builtin_amdgcn_mfma_f32_16x16x32_bf16(af1b, bfb, acc1, 0, 0, 0);
        acc2 = __builtin_amdgcn_mfma_f32_16x16x32_bf16(af2a, bfa, acc2, 0, 0, 0);
        acc2 = __builtin_amdgcn_mfma_f32_16x16x32_bf16(af2b, bfb, acc2, 0, 0, 0);
        acc3 = __builtin_amdgcn_mfma_f32_16x16x32_bf16(af3a, bfa, acc3, 0, 0, 0);
        acc3 = __builtin_amdgcn_mfma_f32_16x16x32_bf16(af3b, bfb, acc3, 0, 0, 0);
    }

    // ---- reduce: waves 1,2 park partials in LDS; wave 0 sums + bias + stores ----
    if (u > 0) {
        float* rp = &red[u - 1][lane][0];
        *(f32x4*)(rp + 0)  = acc0;
        *(f32x4*)(rp + 4)  = acc1;
        *(f32x4*)(rp + 8)  = acc2;
        *(f32x4*)(rp + 12) = acc3;
    }
    __syncthreads();
    if (u == 0) {
        float* __restrict__ op = out + (size_t)b * Con * HW + pix0 + px;
        const float* rp0 = &red[0][lane][0];
        const float* rp1 = &red[1][lane][0];
        const int orow = q * 4;
        #pragma unroll
        for (int s = 0; s < 4; ++s) {
            f32x4 a;
            if (s == 0) a = acc0; else if (s == 1) a = acc1;
            else if (s == 2) a = acc2; else a = acc3;
            const f32x4 r0 = *(const f32x4*)(rp0 + s * 4);
            const f32x4 r1 = *(const f32x4*)(rp1 + s * 4);
            const f32x4 bv = *(const f32x4*)&bias[s * 16 + orow];
            #pragma unroll
            for (int r = 0; r < 4; ++r)
                op[(size_t)(s * 16 + orow + r) * HW] = a[r] + r0[r] + r1[r] + bv[r];
        }
    }
}

// ---------------- fallback (round-1 fp32 fused, used only if ws too small) ----------------
__global__ __launch_bounds__(256) void dcnv2_fused(
    const float* __restrict__ input, const float* __restrict__ offset,
    const float* __restrict__ mask, const float* __restrict__ weight,
    const float* __restrict__ bias, float* __restrict__ out)
{
    __shared__ float s_w[PIX*Kk][4];
    __shared__ int   s_a[PIX*Kk][4];
    __shared__ float s_samp[CK*PIX];
    const int t = threadIdx.x, blk = blockIdx.x;
    const int b = blk / NTILE, tile = blk % NTILE;
    const int pix0 = tile * PIX, ho = pix0 / Wn, wo0 = pix0 % Wn;
    if (t < PIX*Kk) {
        const int p = t / Kk, k = t - p*Kk, wo = wo0 + p, sp = ho*Wn + wo;
        const float dy = offset[(size_t)(b*2*Kk + 2*k)*HW + sp];
        const float dx = offset[(size_t)(b*2*Kk + 2*k + 1)*HW + sp];
        const float m  = mask[(size_t)(b*Kk + k)*HW + sp];
        const float py = dy + (float)(k/3) + (float)(ho - 1);
        const float px = dx + (float)(k%3) + (float)(wo - 1);
        const float fy = floorf(py), fx = floorf(px);
        const int iy0 = (int)fy, ix0 = (int)fx, iy1 = iy0+1, ix1 = ix0+1;
        const float wy = py - fy, wx = px - fx;
        const float vy0 = (iy0>=0 && iy0<Hn)?1.f:0.f, vy1 = (iy1>=0 && iy1<Hn)?1.f:0.f;
        const float vx0 = (ix0>=0 && ix0<Wn)?1.f:0.f, vx1 = (ix1>=0 && ix1<Wn)?1.f:0.f;
        const int cy0 = min(max(iy0,0),Hn-1), cy1 = min(max(iy1,0),Hn-1);
        const int cx0 = min(max(ix0,0),Wn-1), cx1 = min(max(ix1,0),Wn-1);
        s_w[t][0]=m*(1.f-wy)*(1.f-wx)*vy0*vx0; s_w[t][1]=m*(1.f-wy)*wx*vy0*vx1;
        s_w[t][2]=m*wy*(1.f-wx)*vy1*vx0;       s_w[t][3]=m*wy*wx*vy1*vx1;
        s_a[t][0]=cy0*Wn+cx0; s_a[t][1]=cy0*Wn+cx1; s_a[t][2]=cy1*Wn+cx0; s_a[t][3]=cy1*Wn+cx1;
    }
    __syncthreads();
    {
        const float* inb = input + (size_t)b*Cn*HW;
        #pragma unroll 4
        for (int e = t; e < CK*PIX; e += 256) {
            const int ck = e >> 4, p = e & 15, c = ck / 9, k = ck - c*9, pk = p*Kk + k;
            const float* ic = inb + (size_t)c*HW;
            s_samp[ck*PIX + p] = s_w[pk][0]*ic[s_a[pk][0]] + s_w[pk][1]*ic[s_a[pk][1]]
                               + s_w[pk][2]*ic[s_a[pk][2]] + s_w[pk][3]*ic[s_a[pk][3]];
        }
    }
    __syncthreads();
    const int o = t & 63, pg = t >> 6;
    const float4* wrow = (const float4*)(weight + (size_t)o*CK);
    float ax=0.f, ay=0.f, az=0.f, aw=0.f;
    #pragma unroll 4
    for (int qq = 0; qq < CK/4; ++qq) {
        const float4 wv = wrow[qq];
        const float4 s0 = *(const float4*)&s_samp[(4*qq+0)*PIX + pg*4];
        const float4 s1 = *(const float4*)&s_samp[(4*qq+1)*PIX + pg*4];
        const float4 s2 = *(const float4*)&s_samp[(4*qq+2)*PIX + pg*4];
        const float4 s3 = *(const float4*)&s_samp[(4*qq+3)*PIX + pg*4];
        ax += wv.x*s0.x + wv.y*s1.x + wv.z*s2.x + wv.w*s3.x;
        ay += wv.x*s0.y + wv.y*s1.y + wv.z*s2.y + wv.w*s3.y;
        az += wv.x*s0.z + wv.y*s1.z + wv.z*s2.z + wv.w*s3.z;
        aw += wv.x*s0.w + wv.y*s1.w + wv.z*s2.w + wv.w*s3.w;
    }
    const float bo = bias[o];
    float* op = out + (size_t)(b*Con + o)*HW + pix0 + pg*4;
    op[0]=ax+bo; op[1]=ay+bo; op[2]=az+bo; op[3]=aw+bo;
}

extern "C" void kernel_launch(void* const* d_in, const int* in_sizes, int n_in,
                              void* d_out, int out_size, void* d_ws, size_t ws_size,
                              hipStream_t stream) {
    const float* input  = (const float*)d_in[0];
    const float* offset = (const float*)d_in[1];
    const float* mask   = (const float*)d_in[2];
    const float* weight = (const float*)d_in[3];
    const float* bias   = (const float*)d_in[4];
    float* out = (float*)d_out;

    const size_t nhwc_bytes = (size_t)Bn * HW * 64 * 2;          // 4,718,592
    const size_t wb_bytes   = (size_t)Con * CK * 2;              // 73,728
    if (ws_size >= nhwc_bytes + wb_bytes) {
        ushort* nhwc = (ushort*)d_ws;
        ushort* wbuf = (ushort*)((char*)d_ws + nhwc_bytes);
        hipLaunchKernelGGL(dcnv2_prep, dim3(720), dim3(256), 0, stream,
                           input, weight, nhwc, wbuf);
        hipLaunchKernelGGL(dcnv2_main, dim3(Bn * NTILE), dim3(192), 0, stream,
                           nhwc, wbuf, offset, mask, bias, out);
    } else {
        hipLaunchKernelGGL(dcnv2_fused, dim3(Bn * NTILE), dim3(256), 0, stream,
                           input, offset, mask, weight, bias, out);
    }
}